// Round 1
// baseline (48145.728 us; speedup 1.0000x reference)
//
#include <hip/hip_runtime.h>
#include <hip/hip_cooperative_groups.h>

namespace cg = cooperative_groups;

// Problem dims
constexpr int BB = 64;          // batch
constexpr int TT = 512;         // time
constexpr int DD = 512;         // input dim
constexpr int HH = 512;         // hidden
constexpr int GG = 4 * HH;      // 2048 gate columns (i,f,g,o)
constexpr int KK = DD + HH;     // 1024 unified K ([x | h])

// ws layout: WT [GG][KK] f32 (8 MB), then hbuf[2][BB*HH] f32 (256 KB)

__global__ void prep_kernel(const float* __restrict__ Wx,   // [DD][GG]
                            const float* __restrict__ Wr,   // [HH][GG]
                            const float* __restrict__ init_h,
                            float* __restrict__ WT,         // [GG][KK]
                            float* __restrict__ hbuf0) {
    int idx = blockIdx.x * blockDim.x + threadIdx.x;
    if (idx < GG * KK) {
        int g = idx >> 10;          // / KK
        int k = idx & (KK - 1);
        WT[idx] = (k < DD) ? Wx[(size_t)k * GG + g]
                           : Wr[(size_t)(k - DD) * GG + g];
    }
    if (idx < BB * HH) hbuf0[idx] = init_h[idx];
}

__global__ void __launch_bounds__(256)
lstm_kernel(const float* __restrict__ x,      // [B,T,D]
            const float* __restrict__ WT,     // [GG][KK]
            const float* __restrict__ bias,   // [GG]
            const int*   __restrict__ mask,   // [B,T] (bool -> int32)
            const float* __restrict__ init_h, // [B,H]
            const float* __restrict__ init_c, // [B,H]
            float*       hbuf,                // [2][B*H]
            float* __restrict__ out)          // outputs | h_f | c_f
{
    cg::grid_group grid = cg::this_grid();

    const int bid = blockIdx.x;
    const int bg  = bid >> 6;        // 0..3  batch group (16 rows)
    const int js  = bid & 63;        // 0..63 j slice (8 cols)
    const int b0  = bg * 16;
    const int j0  = js * 8;
    const int tid = threadIdx.x;

    // ---- compute-phase mapping: thread -> (rows bi, bi+8) x (gate col gc)
    const int gc   = tid & 31;       // 0..31 = gate(0..3) * 8 + jj
    const int bi   = tid >> 5;       // 0..7
    const int gate = gc >> 3;
    const int jj   = gc & 7;
    const int g    = gate * HH + j0 + jj;          // global gate column
    const float4* __restrict__ w4  = reinterpret_cast<const float4*>(WT + (size_t)g * KK);
    const float4* __restrict__ w4h = w4 + DD / 4;
    const float bz = bias[g];

    // ---- update-phase mapping (tid < 128): one (b, j) element, state in regs
    const int ub   = tid >> 3;       // 0..15
    const int uj   = tid & 7;        // 0..7
    const int brow = b0 + ub;
    float c_reg = 0.f, h_reg = 0.f, po_reg = 0.f;
    if (tid < 128) {
        c_reg = init_c[brow * HH + j0 + uj];
        h_reg = init_h[brow * HH + j0 + uj];
    }

    __shared__ float z_lds[16][33];  // [b-row][gate col], padded

    const size_t OUT_HF = (size_t)BB * TT * HH;
    const size_t OUT_CF = OUT_HF + (size_t)BB * HH;

    for (int t = 0; t < TT; ++t) {
        const float* cur = hbuf + (size_t)(t & 1) * (BB * HH);
        float*       nxt = hbuf + (size_t)((t + 1) & 1) * (BB * HH);

        // ---- z[b, g] = bias + x[t,b,:]@Wx[:,g] + h[b,:]@Wr[:,g]
        float s0 = 0.f, s1 = 0.f, s2 = 0.f, s3 = 0.f;
        float r0 = 0.f, r1 = 0.f, r2 = 0.f, r3 = 0.f;

        const float4* a0p = reinterpret_cast<const float4*>(
            x + ((size_t)(b0 + bi) * TT + t) * DD);
        const float4* a1p = reinterpret_cast<const float4*>(
            x + ((size_t)(b0 + bi + 8) * TT + t) * DD);
        #pragma unroll 4
        for (int kk = 0; kk < DD / 4; ++kk) {
            float4 wv = w4[kk];
            float4 a0 = a0p[kk];
            float4 a1 = a1p[kk];
            s0 = fmaf(a0.x, wv.x, s0); s1 = fmaf(a0.y, wv.y, s1);
            s2 = fmaf(a0.z, wv.z, s2); s3 = fmaf(a0.w, wv.w, s3);
            r0 = fmaf(a1.x, wv.x, r0); r1 = fmaf(a1.y, wv.y, r1);
            r2 = fmaf(a1.z, wv.z, r2); r3 = fmaf(a1.w, wv.w, r3);
        }

        const float4* h0p = reinterpret_cast<const float4*>(cur + (b0 + bi) * HH);
        const float4* h1p = reinterpret_cast<const float4*>(cur + (b0 + bi + 8) * HH);
        #pragma unroll 4
        for (int kk = 0; kk < HH / 4; ++kk) {
            float4 wv = w4h[kk];
            float4 a0 = h0p[kk];
            float4 a1 = h1p[kk];
            s0 = fmaf(a0.x, wv.x, s0); s1 = fmaf(a0.y, wv.y, s1);
            s2 = fmaf(a0.z, wv.z, s2); s3 = fmaf(a0.w, wv.w, s3);
            r0 = fmaf(a1.x, wv.x, r0); r1 = fmaf(a1.y, wv.y, r1);
            r2 = fmaf(a1.z, wv.z, r2); r3 = fmaf(a1.w, wv.w, r3);
        }

        z_lds[bi][gc]     = bz + ((s0 + s1) + (s2 + s3));
        z_lds[bi + 8][gc] = bz + ((r0 + r1) + (r2 + r3));
        __syncthreads();

        // ---- gate nonlinearities + state update (Keras gate order i,f,g,o)
        if (tid < 128) {
            float zi = z_lds[ub][uj];
            float zf = z_lds[ub][8 + uj];
            float zg = z_lds[ub][16 + uj];
            float zo = z_lds[ub][24 + uj];

            float ig = 1.f / (1.f + expf(-zi));
            float fg = 1.f / (1.f + expf(-zf));
            float gg = tanhf(zg);
            float og = 1.f / (1.f + expf(-zo));

            float c_new = fg * c_reg + ig * gg;
            float h_new = og * tanhf(c_new);

            bool m = (mask[brow * TT + t] != 0);
            float ov = m ? h_new : po_reg;   // out  = where(m, h_new, prev_out)
            float h2 = m ? h_new : h_reg;    // h    = where(m, h_new, h)
            float c2 = m ? c_new : c_reg;    // c    = where(m, c_new, c)

            out[((size_t)brow * TT + t) * HH + j0 + uj] = ov;
            nxt[brow * HH + j0 + uj] = h2;

            c_reg = c2; h_reg = h2; po_reg = ov;
        }

        __threadfence();   // make h writes device-visible before the barrier
        grid.sync();       // all blocks: h[t+1] complete, LDS reusable
    }

    if (tid < 128) {
        out[OUT_HF + brow * HH + j0 + uj] = h_reg;
        out[OUT_CF + brow * HH + j0 + uj] = c_reg;
    }
}

extern "C" void kernel_launch(void* const* d_in, const int* in_sizes, int n_in,
                              void* d_out, int out_size, void* d_ws, size_t ws_size,
                              hipStream_t stream) {
    const float* x      = (const float*)d_in[0];
    const float* init_h = (const float*)d_in[1];
    const float* init_c = (const float*)d_in[2];
    const float* Wx     = (const float*)d_in[3];
    const float* Wr     = (const float*)d_in[4];
    const float* bias   = (const float*)d_in[5];
    const int*   mask   = (const int*)d_in[6];
    float* out  = (float*)d_out;

    float* WT   = (float*)d_ws;                    // GG*KK f32 = 8 MB
    float* hbuf = WT + (size_t)GG * KK;            // 2*BB*HH f32 = 256 KB

    prep_kernel<<<(GG * KK + 255) / 256, 256, 0, stream>>>(Wx, Wr, init_h, WT, hbuf);

    void* args[] = { (void*)&x, (void*)&WT, (void*)&bias, (void*)&mask,
                     (void*)&init_h, (void*)&init_c, (void*)&hbuf, (void*)&out };
    hipLaunchCooperativeKernel((const void*)lstm_kernel, dim3(256), dim3(256),
                               args, 0, stream);
}